// Round 1
// baseline (9326.334 us; speedup 1.0000x reference)
//
#include <hip/hip_runtime.h>
#include <math.h>

// Problem constants
#define DMODEL 256
#define NHEADS 8
#define NLVL 4
#define NPT 4
#define NLAY 6
#define DFF 1024
#define DHEAD 32
#define NB 2
#define STOT 21760
#define MTOT (NB * STOT)   // 43520

// Level geometry: SHAPES = [(128,128),(64,64),(32,32),(16,16)]
// starts: 0, 16384, 20480, 21504

// ---------------------------------------------------------------------------
// Flatten: src[b,d,y,x] -> out[b, s, d]; pos likewise + level_embed[l][d]
// 32x32 LDS transpose tiles. Grid: (HW/32, D/32, B)
// ---------------------------------------------------------------------------
__global__ __launch_bounds__(256)
void flatten_kernel(const float* __restrict__ src, const float* __restrict__ pos,
                    const float* __restrict__ le_row,   // level_embed + l*D
                    float* __restrict__ out, float* __restrict__ posf,
                    int HW, int start)
{
    __shared__ float ts[32][33];
    __shared__ float tp[32][33];
    const int b   = blockIdx.z;
    const int d0  = blockIdx.y * 32;
    const int hw0 = blockIdx.x * 32;
    const int t   = threadIdx.x;
    const int hwl = t & 31;
    const int dl  = t >> 5;   // 0..7
#pragma unroll
    for (int p = 0; p < 4; ++p) {
        const int dd = dl + p * 8;
        const int d  = d0 + dd;
        const long idx = ((long)(b * DMODEL + d)) * HW + hw0 + hwl;
        ts[dd][hwl] = src[idx];
        tp[dd][hwl] = pos[idx] + le_row[d];
    }
    __syncthreads();
    const int dl2  = t & 31;
    const int hwl2 = t >> 5;
#pragma unroll
    for (int p = 0; p < 4; ++p) {
        const int hh  = hwl2 + p * 8;
        const int tok = start + hw0 + hh;
        const long o  = ((long)(b * STOT + tok)) * DMODEL + d0 + dl2;
        out[o]  = ts[dl2][hh];
        posf[o] = tp[dl2][hh];
    }
}

// ---------------------------------------------------------------------------
// Generic f32 tiled GEMM:  C[M,N] = (A1 (+A2)) [M,K] @ W[K x N, row stride ldw]
//   (+ bias[N]) (+= old C if accum) (relu if relu)
// BM=BN=64, BK=32, 256 threads, 4x4 per thread. M multiple of 64 via grid.y,
// N multiple of 64 via grid.x, K multiple of 32.
// ---------------------------------------------------------------------------
__global__ __launch_bounds__(256)
void gemm_kernel(const float* __restrict__ A1, const float* __restrict__ A2,
                 const float* __restrict__ W, const int ldw,
                 const float* __restrict__ bias,
                 float* __restrict__ C, const int N, const int K,
                 const int relu, const int accum)
{
    __shared__ float As[64][33];   // [m][k]
    __shared__ float Ws[32][68];   // [k][n], 68 pad keeps b128 aligned + conflict-free
    const int tid = threadIdx.x;
    const int m0 = blockIdx.y * 64;
    const int n0 = blockIdx.x * 64;
    const int tx = tid & 15, ty = tid >> 4;
    float acc[4][4] = {};

    const int arow = tid >> 3;        // 0..31
    const int ak4  = (tid & 7) * 4;   // 0,4,...,28
    const int wrow = tid >> 4;        // 0..15
    const int wn4  = (tid & 15) * 4;  // 0,4,...,60

    for (int k0 = 0; k0 < K; k0 += 32) {
#pragma unroll
        for (int it = 0; it < 2; ++it) {
            const int m = arow + it * 32;
            float4 v = *(const float4*)(A1 + (long)(m0 + m) * K + k0 + ak4);
            if (A2) {
                const float4 v2 = *(const float4*)(A2 + (long)(m0 + m) * K + k0 + ak4);
                v.x += v2.x; v.y += v2.y; v.z += v2.z; v.w += v2.w;
            }
            As[m][ak4 + 0] = v.x; As[m][ak4 + 1] = v.y;
            As[m][ak4 + 2] = v.z; As[m][ak4 + 3] = v.w;
        }
#pragma unroll
        for (int it = 0; it < 2; ++it) {
            const int kk = wrow + it * 16;
            const float4 v = *(const float4*)(W + (long)(k0 + kk) * ldw + n0 + wn4);
            *(float4*)&Ws[kk][wn4] = v;
        }
        __syncthreads();
#pragma unroll
        for (int k = 0; k < 32; ++k) {
            float a[4], bb[4];
#pragma unroll
            for (int i = 0; i < 4; ++i) a[i] = As[ty * 4 + i][k];
            const float4 bv = *(const float4*)&Ws[k][tx * 4];
            bb[0] = bv.x; bb[1] = bv.y; bb[2] = bv.z; bb[3] = bv.w;
#pragma unroll
            for (int i = 0; i < 4; ++i)
#pragma unroll
                for (int j = 0; j < 4; ++j)
                    acc[i][j] = fmaf(a[i], bb[j], acc[i][j]);
        }
        __syncthreads();
    }

#pragma unroll
    for (int i = 0; i < 4; ++i) {
        const int m = m0 + ty * 4 + i;
        float* cp = C + (long)m * N + n0 + tx * 4;
        float4 r;
        r.x = acc[i][0]; r.y = acc[i][1]; r.z = acc[i][2]; r.w = acc[i][3];
        if (bias) {
            const float4 b4 = *(const float4*)(bias + n0 + tx * 4);
            r.x += b4.x; r.y += b4.y; r.z += b4.z; r.w += b4.w;
        }
        if (accum) {
            const float4 c0 = *(const float4*)cp;
            r.x += c0.x; r.y += c0.y; r.z += c0.z; r.w += c0.w;
        }
        if (relu) {
            r.x = fmaxf(r.x, 0.f); r.y = fmaxf(r.y, 0.f);
            r.z = fmaxf(r.z, 0.f); r.w = fmaxf(r.w, 0.f);
        }
        *(float4*)cp = r;
    }
}

// ---------------------------------------------------------------------------
// Softmax over 16 (l,p) logits per (b,s,head), in place. One thread per row.
// ---------------------------------------------------------------------------
__global__ __launch_bounds__(256)
void softmax16_kernel(float* __restrict__ logits)
{
    const int r = blockIdx.x * 256 + threadIdx.x;
    if (r >= MTOT * NHEADS) return;
    float v[16];
    float mx = -1e30f;
#pragma unroll
    for (int i = 0; i < 16; ++i) { v[i] = logits[(long)r * 16 + i]; mx = fmaxf(mx, v[i]); }
    float s = 0.f;
#pragma unroll
    for (int i = 0; i < 16; ++i) { v[i] = expf(v[i] - mx); s += v[i]; }
    const float inv = 1.f / s;
#pragma unroll
    for (int i = 0; i < 16; ++i) logits[(long)r * 16 + i] = v[i] * inv;
}

// ---------------------------------------------------------------------------
// Deformable sampling. One block per token (b,s); 256 threads = 8 heads x 32 ch.
// out[b,s, h*32+ch] = sum_{l,p} aw * bilinear(value level l, loc)
// ---------------------------------------------------------------------------
__global__ __launch_bounds__(256)
void sample_kernel(const float* __restrict__ value, const float* __restrict__ off,
                   const float* __restrict__ aw, float* __restrict__ out)
{
    constexpr int LH[4] = {128, 64, 32, 16};
    constexpr int LW[4] = {128, 64, 32, 16};
    constexpr int LS[4] = {0, 16384, 20480, 21504};

    const int blk = blockIdx.x;         // b*STOT + s
    const int b = blk / STOT;
    const int s = blk - b * STOT;
    const int t = threadIdx.x;
    const int h = t >> 5;
    const int lane = t & 31;

    // reference point of this token (same across level axis)
    float refx, refy;
    if (s < 16384) {
        const int sl = s;        const int yy = sl >> 7, xx = sl & 127;
        refx = (xx + 0.5f) * (1.f / 128.f); refy = (yy + 0.5f) * (1.f / 128.f);
    } else if (s < 20480) {
        const int sl = s - 16384; const int yy = sl >> 6, xx = sl & 63;
        refx = (xx + 0.5f) * (1.f / 64.f);  refy = (yy + 0.5f) * (1.f / 64.f);
    } else if (s < 21504) {
        const int sl = s - 20480; const int yy = sl >> 5, xx = sl & 31;
        refx = (xx + 0.5f) * (1.f / 32.f);  refy = (yy + 0.5f) * (1.f / 32.f);
    } else {
        const int sl = s - 21504; const int yy = sl >> 4, xx = sl & 15;
        refx = (xx + 0.5f) * (1.f / 16.f);  refy = (yy + 0.5f) * (1.f / 16.f);
    }

    const float* offp = off + (long)blk * 256 + h * 32;  // [NL][NP][2] for this head
    const float* awp  = aw  + (long)blk * 128 + h * 16;  // [NL][NP]
    float acc = 0.f;
#pragma unroll
    for (int l = 0; l < 4; ++l) {
        const int lw = LW[l], lh = LH[l], ls = LS[l];
        const float* vbase = value + ((long)(b * STOT + ls)) * DMODEL + h * DHEAD + lane;
#pragma unroll
        for (int p = 0; p < 4; ++p) {
            const float ox = offp[(l * 4 + p) * 2 + 0];
            const float oy = offp[(l * 4 + p) * 2 + 1];
            const float a  = awp[l * 4 + p];
            // x = (refx + ox/w)*w - 0.5 = refx*w + ox - 0.5
            const float x = refx * lw + ox - 0.5f;
            const float y = refy * lh + oy - 0.5f;
            const float x0f = floorf(x), y0f = floorf(y);
            const float lx = x - x0f, ly = y - y0f;
            const int x0 = (int)x0f, y0 = (int)y0f;
#pragma unroll
            for (int dy = 0; dy < 2; ++dy) {
                const int yi = y0 + dy;
                if (yi < 0 || yi >= lh) continue;
                const float wy = dy ? ly : (1.f - ly);
#pragma unroll
                for (int dx = 0; dx < 2; ++dx) {
                    const int xi = x0 + dx;
                    if (xi < 0 || xi >= lw) continue;
                    const float wx = dx ? lx : (1.f - lx);
                    const float v = vbase[(long)(yi * lw + xi) * DMODEL];
                    acc = fmaf(a * wy * wx, v, acc);
                }
            }
        }
    }
    out[(long)blk * DMODEL + t] = acc;
}

// ---------------------------------------------------------------------------
// out = LayerNorm(out + delta) * gamma + beta  (in place on out)
// Block = 4 waves; each wave handles one token; lane holds float4 (64*4=256).
// ---------------------------------------------------------------------------
__global__ __launch_bounds__(256)
void ln_kernel(float* __restrict__ out, const float* __restrict__ delta,
               const float* __restrict__ gamma, const float* __restrict__ beta)
{
    const int wave = threadIdx.x >> 6;
    const int lane = threadIdx.x & 63;
    const long tok = (long)blockIdx.x * 4 + wave;
    float* op = out + tok * DMODEL + lane * 4;
    const float4 xo = *(const float4*)op;
    const float4 dd = *(const float4*)(delta + tok * DMODEL + lane * 4);
    float x[4] = {xo.x + dd.x, xo.y + dd.y, xo.z + dd.z, xo.w + dd.w};

    float sum = x[0] + x[1] + x[2] + x[3];
#pragma unroll
    for (int o = 32; o >= 1; o >>= 1) sum += __shfl_xor(sum, o);
    const float mean = sum * (1.f / 256.f);

    float vs = 0.f;
#pragma unroll
    for (int i = 0; i < 4; ++i) { const float d2 = x[i] - mean; vs += d2 * d2; }
#pragma unroll
    for (int o = 32; o >= 1; o >>= 1) vs += __shfl_xor(vs, o);
    const float rstd = rsqrtf(vs * (1.f / 256.f) + 1e-5f);

    const float4 g = *(const float4*)(gamma + lane * 4);
    const float4 be = *(const float4*)(beta + lane * 4);
    float4 r;
    r.x = (x[0] - mean) * rstd * g.x + be.x;
    r.y = (x[1] - mean) * rstd * g.y + be.y;
    r.z = (x[2] - mean) * rstd * g.z + be.z;
    r.w = (x[3] - mean) * rstd * g.w + be.w;
    *(float4*)op = r;
}

// ---------------------------------------------------------------------------
extern "C" void kernel_launch(void* const* d_in, const int* in_sizes, int n_in,
                              void* d_out, int out_size, void* d_ws, size_t ws_size,
                              hipStream_t stream)
{
    // setup_inputs() dict order:
    const float* src[4] = {(const float*)d_in[0], (const float*)d_in[2],
                           (const float*)d_in[4], (const float*)d_in[6]};
    const float* pos[4] = {(const float*)d_in[1], (const float*)d_in[3],
                           (const float*)d_in[5], (const float*)d_in[7]};
    const float* level_embed = (const float*)d_in[8];
    const float* Woff  = (const float*)d_in[9];
    const float* boff  = (const float*)d_in[10];
    const float* Wattn = (const float*)d_in[11];
    const float* battn = (const float*)d_in[12];
    const float* Wval  = (const float*)d_in[13];
    const float* bval  = (const float*)d_in[14];
    const float* Wout  = (const float*)d_in[15];
    const float* bout  = (const float*)d_in[16];
    const float* ln1s  = (const float*)d_in[17];
    const float* ln1b  = (const float*)d_in[18];
    const float* W1    = (const float*)d_in[19];
    const float* b1    = (const float*)d_in[20];
    const float* W2    = (const float*)d_in[21];
    const float* b2    = (const float*)d_in[22];
    const float* ln2s  = (const float*)d_in[23];
    const float* ln2b  = (const float*)d_in[24];

    float* out = (float*)d_out;                 // [B,S,D] working memory
    float* ws  = (float*)d_ws;
    // ws layout (floats): posf | v_buf | o_buf | s_buf | aw_buf  = 200.5 MB
    float* posf   = ws;                          // [MTOT,256] pos_flat (persistent)
    float* v_buf  = posf  + (long)MTOT * DMODEL; // value, later Wout-result / FF acc
    float* o_buf  = v_buf + (long)MTOT * DMODEL; // offsets, later FF hidden chunk
    float* s_buf  = o_buf + (long)MTOT * DMODEL; // sampled attention output
    float* aw_buf = s_buf + (long)MTOT * DMODEL; // [MTOT,128] attn weights

    // ---- flatten src/pos into token-major layout ----
    {
        const int HW[4] = {16384, 4096, 1024, 256};
        const int ST[4] = {0, 16384, 20480, 21504};
        for (int l = 0; l < 4; ++l) {
            dim3 g(HW[l] / 32, DMODEL / 32, NB);
            flatten_kernel<<<g, 256, 0, stream>>>(src[l], pos[l],
                                                  level_embed + l * DMODEL,
                                                  out, posf, HW[l], ST[l]);
        }
    }

    const dim3 g64(4, MTOT / 64);          // N=256 GEMMs
    const dim3 g64h(2, MTOT / 64);         // N=128 GEMM (attn logits)

    for (int i = 0; i < NLAY; ++i) {
        const float* Wv  = Wval  + (long)i * DMODEL * DMODEL;
        const float* bv  = bval  + (long)i * DMODEL;
        const float* Wo  = Woff  + (long)i * DMODEL * 256;
        const float* bo  = boff  + (long)i * 256;
        const float* Wa  = Wattn + (long)i * DMODEL * 128;
        const float* ba  = battn + (long)i * 128;
        const float* Wou = Wout  + (long)i * DMODEL * DMODEL;
        const float* bou = bout  + (long)i * DMODEL;
        const float* W1i = W1    + (long)i * DMODEL * DFF;
        const float* b1i = b1    + (long)i * DFF;
        const float* W2i = W2    + (long)i * DFF * DMODEL;
        const float* b2i = b2    + (long)i * DMODEL;

        // value = out @ Wval + bval
        gemm_kernel<<<g64, 256, 0, stream>>>(out, nullptr, Wv, DMODEL, bv,
                                             v_buf, DMODEL, DMODEL, 0, 0);
        // off = (out+pos) @ Woff + boff
        gemm_kernel<<<g64, 256, 0, stream>>>(out, posf, Wo, 256, bo,
                                             o_buf, 256, DMODEL, 0, 0);
        // attn logits = (out+pos) @ Wattn + battn
        gemm_kernel<<<g64h, 256, 0, stream>>>(out, posf, Wa, 128, ba,
                                              aw_buf, 128, DMODEL, 0, 0);
        softmax16_kernel<<<(MTOT * NHEADS) / 256, 256, 0, stream>>>(aw_buf);
        sample_kernel<<<MTOT, 256, 0, stream>>>(v_buf, o_buf, aw_buf, s_buf);
        // attn_out @ Wout + bout -> v_buf (value no longer needed)
        gemm_kernel<<<g64, 256, 0, stream>>>(s_buf, nullptr, Wou, DMODEL, bou,
                                             v_buf, DMODEL, DMODEL, 0, 0);
        // out = LN(out + v_buf)
        ln_kernel<<<MTOT / 4, 256, 0, stream>>>(out, v_buf,
                                                ln1s + (long)i * DMODEL,
                                                ln1b + (long)i * DMODEL);
        // FF: chunk DFF into 4 x 256 to keep workspace small
        for (int c = 0; c < 4; ++c) {
            // h_c = relu(out @ W1[:, c*256:(c+1)*256] + b1[c*256:...])
            gemm_kernel<<<g64, 256, 0, stream>>>(out, nullptr, W1i + c * 256, DFF,
                                                 b1i + c * 256, o_buf, 256, DMODEL,
                                                 1, 0);
            // v_buf (c==0: = h_c @ W2_c + b2) (c>0: += h_c @ W2_c)
            gemm_kernel<<<g64, 256, 0, stream>>>(o_buf, nullptr,
                                                 W2i + (long)c * 256 * DMODEL, DMODEL,
                                                 (c == 0) ? b2i : nullptr,
                                                 v_buf, DMODEL, 256, 0, c > 0);
        }
        // out = LN(out + v_buf)
        ln_kernel<<<MTOT / 4, 256, 0, stream>>>(out, v_buf,
                                                ln2s + (long)i * DMODEL,
                                                ln2b + (long)i * DMODEL);
    }
}

// Round 3
// 4846.215 us; speedup vs baseline: 1.9245x; 1.9245x over previous
//
#include <hip/hip_runtime.h>
#include <math.h>

// Problem constants
#define DMODEL 256
#define NHEADS 8
#define NLAY 6
#define DFF 1024
#define DHEAD 32
#define NB 2
#define STOT 21760
#define MTOT (NB * STOT)   // 43520 = 128 * 340

typedef unsigned short u16;
typedef __attribute__((ext_vector_type(8))) short short8;
typedef __attribute__((ext_vector_type(4))) float floatx4;

__device__ __forceinline__ float bf2f(u16 h) {
    unsigned int u = ((unsigned int)h) << 16;
    return __uint_as_float(u);
}
__device__ __forceinline__ u16 f2bf(float f) {
    unsigned int u = __float_as_uint(f);
    u = u + 0x7fffu + ((u >> 16) & 1u);   // RNE
    return (u16)(u >> 16);
}
__device__ __forceinline__ unsigned int addbf2(unsigned int a, unsigned int b) {
    const float lo = bf2f((u16)(a & 0xffffu)) + bf2f((u16)(b & 0xffffu));
    const float hi = bf2f((u16)(a >> 16))     + bf2f((u16)(b >> 16));
    return (unsigned int)f2bf(lo) | ((unsigned int)f2bf(hi) << 16);
}

// ---------------------------------------------------------------------------
// Weight transpose + bf16 cast: W[K,N] f32 -> Wt[N,K] bf16. grid(N/32,K/32,NLAY)
// ---------------------------------------------------------------------------
__global__ __launch_bounds__(256)
void wtrans_kernel(const float* __restrict__ W, u16* __restrict__ Wt,
                   const int K, const int N)
{
    __shared__ float ts[32][33];
    const long lstride = (long)K * N;
    W  += blockIdx.z * lstride;
    Wt += blockIdx.z * lstride;
    const int n0 = blockIdx.x * 32;
    const int k0 = blockIdx.y * 32;
    const int t = threadIdx.x;
    const int nl = t & 31, kl = t >> 5;        // kl 0..7
#pragma unroll
    for (int p = 0; p < 4; ++p) {
        const int k = kl + p * 8;
        ts[k][nl] = W[(long)(k0 + k) * N + n0 + nl];
    }
    __syncthreads();
    const int c = t & 31, r0 = t >> 5;
#pragma unroll
    for (int p = 0; p < 4; ++p) {
        const int r = r0 + p * 8;
        Wt[(long)(n0 + r) * K + k0 + c] = f2bf(ts[c][r]);
    }
}

// ---------------------------------------------------------------------------
// Flatten: src[b,d,y,x] -> out[b,s,d] (f32 + bf16); pos + level_embed -> bf16
// ---------------------------------------------------------------------------
__global__ __launch_bounds__(256)
void flatten_kernel(const float* __restrict__ src, const float* __restrict__ pos,
                    const float* __restrict__ le_row,
                    float* __restrict__ out, u16* __restrict__ outb,
                    u16* __restrict__ posb, int HW, int start)
{
    __shared__ float ts[32][33];
    __shared__ float tp[32][33];
    const int b   = blockIdx.z;
    const int d0  = blockIdx.y * 32;
    const int hw0 = blockIdx.x * 32;
    const int t   = threadIdx.x;
    const int hwl = t & 31;
    const int dl  = t >> 5;
#pragma unroll
    for (int p = 0; p < 4; ++p) {
        const int dd = dl + p * 8;
        const int d  = d0 + dd;
        const long idx = ((long)(b * DMODEL + d)) * HW + hw0 + hwl;
        ts[dd][hwl] = src[idx];
        tp[dd][hwl] = pos[idx] + le_row[d];
    }
    __syncthreads();
    const int dl2  = t & 31;
    const int hwl2 = t >> 5;
#pragma unroll
    for (int p = 0; p < 4; ++p) {
        const int hh  = hwl2 + p * 8;
        const int tok = start + hw0 + hh;
        const long o  = ((long)(b * STOT + tok)) * DMODEL + d0 + dl2;
        const float v = ts[dl2][hh];
        out[o]  = v;
        outb[o] = f2bf(v);
        posb[o] = f2bf(tp[dl2][hh]);
    }
}

// ---------------------------------------------------------------------------
// bf16 MFMA GEMM: C[M,N] = (A1 (+A2))[M,K]bf16 @ Bt[N,K]bf16^T
// 128x128 tile, BK=32, 256 thr = 4 waves (2x2), each wave 4x4 of 16x16x32 MFMA.
// Optional: bias f32[N], accum (+= Cf), relu, f32 out Cf and/or bf16 out Cb.
// ---------------------------------------------------------------------------
__global__ __launch_bounds__(256)
void mfma_gemm(const u16* __restrict__ A1, const u16* __restrict__ A2,
               const u16* __restrict__ Bt, const int ldb,
               const float* __restrict__ bias,
               float* __restrict__ Cf, u16* __restrict__ Cb, const int ldc,
               const int K, const int relu, const int accum)
{
    __shared__ u16 As[128 * 40];
    __shared__ u16 Bs[128 * 40];
    const int tid  = threadIdx.x;
    const int wv   = tid >> 6;
    const int lane = tid & 63;
    const int m0 = blockIdx.y * 128;
    const int n0 = blockIdx.x * 128;
    const int wm = (wv & 1) * 64;
    const int wn = (wv >> 1) * 64;
    const int q   = lane >> 4;
    const int c16 = lane & 15;

    const int srow = tid >> 2;        // 0..63
    const int scol = (tid & 3) * 8;   // 0,8,16,24

    floatx4 acc[4][4];
#pragma unroll
    for (int i = 0; i < 4; ++i)
#pragma unroll
        for (int j = 0; j < 4; ++j)
            acc[i][j] = (floatx4){0.f, 0.f, 0.f, 0.f};

    union Frag { short8 v; uint2 u[2]; };

    for (int k0 = 0; k0 < K; k0 += 32) {
#pragma unroll
        for (int it = 0; it < 2; ++it) {
            const int r = srow + it * 64;
            uint4 va = *(const uint4*)(A1 + (long)(m0 + r) * K + k0 + scol);
            if (A2) {
                const uint4 v2 = *(const uint4*)(A2 + (long)(m0 + r) * K + k0 + scol);
                va.x = addbf2(va.x, v2.x); va.y = addbf2(va.y, v2.y);
                va.z = addbf2(va.z, v2.z); va.w = addbf2(va.w, v2.w);
            }
            uint2 lo, hi;
            lo.x = va.x; lo.y = va.y; hi.x = va.z; hi.y = va.w;
            *(uint2*)&As[r * 40 + scol]     = lo;
            *(uint2*)&As[r * 40 + scol + 4] = hi;
            const uint4 vb = *(const uint4*)(Bt + (long)(n0 + r) * ldb + k0 + scol);
            lo.x = vb.x; lo.y = vb.y; hi.x = vb.z; hi.y = vb.w;
            *(uint2*)&Bs[r * 40 + scol]     = lo;
            *(uint2*)&Bs[r * 40 + scol + 4] = hi;
        }
        __syncthreads();

        short8 af[4], bf[4];
#pragma unroll
        for (int i = 0; i < 4; ++i) {
            Frag fa;
            const int ao = (wm + i * 16 + c16) * 40 + q * 8;
            fa.u[0] = *(const uint2*)&As[ao];
            fa.u[1] = *(const uint2*)&As[ao + 4];
            af[i] = fa.v;
            Frag fb;
            const int bo = (wn + i * 16 + c16) * 40 + q * 8;
            fb.u[0] = *(const uint2*)&Bs[bo];
            fb.u[1] = *(const uint2*)&Bs[bo + 4];
            bf[i] = fb.v;
        }
#pragma unroll
        for (int i = 0; i < 4; ++i)
#pragma unroll
            for (int j = 0; j < 4; ++j)
                acc[i][j] = __builtin_amdgcn_mfma_f32_16x16x32_bf16(
                    af[i], bf[j], acc[i][j], 0, 0, 0);
        __syncthreads();
    }

#pragma unroll
    for (int i = 0; i < 4; ++i) {
#pragma unroll
        for (int j = 0; j < 4; ++j) {
            const int col = n0 + wn + j * 16 + c16;
            const float bv = bias ? bias[col] : 0.f;
#pragma unroll
            for (int r = 0; r < 4; ++r) {
                const int row = m0 + wm + i * 16 + q * 4 + r;
                float v = acc[i][j][r] + bv;
                const long o = (long)row * ldc + col;
                if (accum) v += Cf[o];
                if (relu)  v = fmaxf(v, 0.f);
                if (Cf) Cf[o] = v;
                if (Cb) Cb[o] = f2bf(v);
            }
        }
    }
}

// ---------------------------------------------------------------------------
// Softmax over 16 (l,p) logits per (b,s,head), in place (f32).
// ---------------------------------------------------------------------------
__global__ __launch_bounds__(256)
void softmax16_kernel(float* __restrict__ logits)
{
    const int r = blockIdx.x * 256 + threadIdx.x;
    if (r >= MTOT * NHEADS) return;
    float v[16];
    float mx = -1e30f;
#pragma unroll
    for (int i = 0; i < 16; ++i) { v[i] = logits[(long)r * 16 + i]; mx = fmaxf(mx, v[i]); }
    float s = 0.f;
#pragma unroll
    for (int i = 0; i < 16; ++i) { v[i] = expf(v[i] - mx); s += v[i]; }
    const float inv = 1.f / s;
#pragma unroll
    for (int i = 0; i < 16; ++i) logits[(long)r * 16 + i] = v[i] * inv;
}

// ---------------------------------------------------------------------------
// Deformable sampling; writes bf16 output for the Wout GEMM.
// One block per token; 256 threads = 8 heads x 32 ch.
// ---------------------------------------------------------------------------
__global__ __launch_bounds__(256)
void sample_kernel(const float* __restrict__ value, const float* __restrict__ off,
                   const float* __restrict__ aw, u16* __restrict__ outb)
{
    constexpr int LH[4] = {128, 64, 32, 16};
    constexpr int LW[4] = {128, 64, 32, 16};
    constexpr int LS[4] = {0, 16384, 20480, 21504};

    const int blk = blockIdx.x;
    const int b = blk / STOT;
    const int s = blk - b * STOT;
    const int t = threadIdx.x;
    const int h = t >> 5;
    const int lane = t & 31;

    float refx, refy;
    if (s < 16384) {
        const int yy = s >> 7, xx = s & 127;
        refx = (xx + 0.5f) * (1.f / 128.f); refy = (yy + 0.5f) * (1.f / 128.f);
    } else if (s < 20480) {
        const int sl = s - 16384; const int yy = sl >> 6, xx = sl & 63;
        refx = (xx + 0.5f) * (1.f / 64.f);  refy = (yy + 0.5f) * (1.f / 64.f);
    } else if (s < 21504) {
        const int sl = s - 20480; const int yy = sl >> 5, xx = sl & 31;
        refx = (xx + 0.5f) * (1.f / 32.f);  refy = (yy + 0.5f) * (1.f / 32.f);
    } else {
        const int sl = s - 21504; const int yy = sl >> 4, xx = sl & 15;
        refx = (xx + 0.5f) * (1.f / 16.f);  refy = (yy + 0.5f) * (1.f / 16.f);
    }

    const float* offp = off + (long)blk * 256 + h * 32;
    const float* awp  = aw  + (long)blk * 128 + h * 16;
    float acc = 0.f;
#pragma unroll
    for (int l = 0; l < 4; ++l) {
        const int lw = LW[l], lh = LH[l], ls = LS[l];
        const float* vbase = value + ((long)(b * STOT + ls)) * DMODEL + h * DHEAD + lane;
#pragma unroll
        for (int p = 0; p < 4; ++p) {
            const float ox = offp[(l * 4 + p) * 2 + 0];
            const float oy = offp[(l * 4 + p) * 2 + 1];
            const float a  = awp[l * 4 + p];
            const float x = refx * lw + ox - 0.5f;
            const float y = refy * lh + oy - 0.5f;
            const float x0f = floorf(x), y0f = floorf(y);
            const float lx = x - x0f, ly = y - y0f;
            const int x0 = (int)x0f, y0 = (int)y0f;
#pragma unroll
            for (int dy = 0; dy < 2; ++dy) {
                const int yi = y0 + dy;
                if (yi < 0 || yi >= lh) continue;
                const float wy = dy ? ly : (1.f - ly);
#pragma unroll
                for (int dx = 0; dx < 2; ++dx) {
                    const int xi = x0 + dx;
                    if (xi < 0 || xi >= lw) continue;
                    const float wx = dx ? lx : (1.f - lx);
                    const float v = vbase[(long)(yi * lw + xi) * DMODEL];
                    acc = fmaf(a * wy * wx, v, acc);
                }
            }
        }
    }
    outb[(long)blk * DMODEL + t] = f2bf(acc);
}

// ---------------------------------------------------------------------------
// out = LayerNorm(out + delta); writes f32 (residual) + bf16 (next GEMM A).
// ---------------------------------------------------------------------------
__global__ __launch_bounds__(256)
void ln_kernel(float* __restrict__ out, u16* __restrict__ outb,
               const float* __restrict__ delta,
               const float* __restrict__ gamma, const float* __restrict__ beta)
{
    const int wave = threadIdx.x >> 6;
    const int lane = threadIdx.x & 63;
    const long tok = (long)blockIdx.x * 4 + wave;
    float* op = out + tok * DMODEL + lane * 4;
    const float4 xo = *(const float4*)op;
    const float4 dd = *(const float4*)(delta + tok * DMODEL + lane * 4);
    float x[4] = {xo.x + dd.x, xo.y + dd.y, xo.z + dd.z, xo.w + dd.w};

    float sum = x[0] + x[1] + x[2] + x[3];
#pragma unroll
    for (int o = 32; o >= 1; o >>= 1) sum += __shfl_xor(sum, o);
    const float mean = sum * (1.f / 256.f);

    float vs = 0.f;
#pragma unroll
    for (int i = 0; i < 4; ++i) { const float d2 = x[i] - mean; vs += d2 * d2; }
#pragma unroll
    for (int o = 32; o >= 1; o >>= 1) vs += __shfl_xor(vs, o);
    const float rstd = rsqrtf(vs * (1.f / 256.f) + 1e-5f);

    const float4 g  = *(const float4*)(gamma + lane * 4);
    const float4 be = *(const float4*)(beta + lane * 4);
    float4 r;
    r.x = (x[0] - mean) * rstd * g.x + be.x;
    r.y = (x[1] - mean) * rstd * g.y + be.y;
    r.z = (x[2] - mean) * rstd * g.z + be.z;
    r.w = (x[3] - mean) * rstd * g.w + be.w;
    *(float4*)op = r;
    ushort4 rb;
    rb.x = f2bf(r.x); rb.y = f2bf(r.y); rb.z = f2bf(r.z); rb.w = f2bf(r.w);
    *(ushort4*)(outb + tok * DMODEL + lane * 4) = rb;
}

// ---------------------------------------------------------------------------
extern "C" void kernel_launch(void* const* d_in, const int* in_sizes, int n_in,
                              void* d_out, int out_size, void* d_ws, size_t ws_size,
                              hipStream_t stream)
{
    const float* src[4] = {(const float*)d_in[0], (const float*)d_in[2],
                           (const float*)d_in[4], (const float*)d_in[6]};
    const float* pos[4] = {(const float*)d_in[1], (const float*)d_in[3],
                           (const float*)d_in[5], (const float*)d_in[7]};
    const float* level_embed = (const float*)d_in[8];
    const float* Woff  = (const float*)d_in[9];
    const float* boff  = (const float*)d_in[10];
    const float* Wattn = (const float*)d_in[11];
    const float* battn = (const float*)d_in[12];
    const float* Wval  = (const float*)d_in[13];
    const float* bval  = (const float*)d_in[14];
    const float* Wout  = (const float*)d_in[15];
    const float* bout  = (const float*)d_in[16];
    const float* ln1s  = (const float*)d_in[17];
    const float* ln1b  = (const float*)d_in[18];
    const float* W1    = (const float*)d_in[19];
    const float* b1    = (const float*)d_in[20];
    const float* W2    = (const float*)d_in[21];
    const float* b2    = (const float*)d_in[22];
    const float* ln2s  = (const float*)d_in[23];
    const float* ln2b  = (const float*)d_in[24];

    float* out = (float*)d_out;                       // residual stream f32
    const long MD = (long)MTOT * DMODEL;              // 11,141,120

    // workspace layout (~188 MB total)
    u16*   outb = (u16*)d_ws;                         // [M,256] bf16
    u16*   posb = outb + MD;                          // [M,256] bf16
    float* R1   = (float*)(posb + MD);                // [M,256] f32: value/attn_out/ff_out
    float* R2f  = R1 + MD;                            // [M,256] f32 offsets  (aliases h)
    u16*   hbuf = (u16*)R2f;                          //   [M,512] bf16 FF hidden chunk
    float* awb  = R2f + MD;                           // [M,128] f32 attn weights
    u16*   sb   = (u16*)(awb + (long)MTOT * 128);     // [M,256] bf16 sampled
    u16*   wts  = sb + MD;                            // bf16 transposed weights
    u16* Wvalt  = wts;
    u16* Wofft  = Wvalt  + 6L * 256 * 256;
    u16* Wattnt = Wofft  + 6L * 256 * 256;
    u16* Woutt  = Wattnt + 6L * 128 * 256;
    u16* W1t    = Woutt  + 6L * 256 * 256;
    u16* W2t    = W1t    + 6L * 1024 * 256;

    // ---- weight transpose+cast (runs every call; ~9 MB total) ----
    wtrans_kernel<<<dim3(8, 8, 6),  256, 0, stream>>>(Wval,  Wvalt,  256, 256);
    wtrans_kernel<<<dim3(8, 8, 6),  256, 0, stream>>>(Woff,  Wofft,  256, 256);
    wtrans_kernel<<<dim3(4, 8, 6),  256, 0, stream>>>(Wattn, Wattnt, 256, 128);
    wtrans_kernel<<<dim3(8, 8, 6),  256, 0, stream>>>(Wout,  Woutt,  256, 256);
    wtrans_kernel<<<dim3(32, 8, 6), 256, 0, stream>>>(W1,    W1t,    256, 1024);
    wtrans_kernel<<<dim3(8, 32, 6), 256, 0, stream>>>(W2,    W2t,    1024, 256);

    // ---- flatten ----
    {
        const int HW[4] = {16384, 4096, 1024, 256};
        const int ST[4] = {0, 16384, 20480, 21504};
        for (int l = 0; l < 4; ++l) {
            dim3 g(HW[l] / 32, DMODEL / 32, NB);
            flatten_kernel<<<g, 256, 0, stream>>>(src[l], pos[l],
                                                  level_embed + l * DMODEL,
                                                  out, outb, posb, HW[l], ST[l]);
        }
    }

    const dim3 g2(2, MTOT / 128);
    const dim3 g1(1, MTOT / 128);
    const dim3 g4(4, MTOT / 128);

    for (int i = 0; i < NLAY; ++i) {
        const u16* Wv  = Wvalt  + (long)i * 256 * 256;
        const u16* Wo  = Wofft  + (long)i * 256 * 256;
        const u16* Wa  = Wattnt + (long)i * 128 * 256;
        const u16* Wou = Woutt  + (long)i * 256 * 256;
        const u16* W1i = W1t    + (long)i * 1024 * 256;
        const u16* W2i = W2t    + (long)i * 256 * 1024;
        const float* bv  = bval  + (long)i * 256;
        const float* bo  = boff  + (long)i * 256;
        const float* ba  = battn + (long)i * 128;
        const float* bou = bout  + (long)i * 256;
        const float* b1i = b1    + (long)i * DFF;
        const float* b2i = b2    + (long)i * 256;

        // value = out @ Wval + bval   -> R1 f32
        mfma_gemm<<<g2, 256, 0, stream>>>(outb, nullptr, Wv, 256, bv,
                                          R1, nullptr, 256, 256, 0, 0);
        // off = (out+pos) @ Woff + boff -> R2 f32
        mfma_gemm<<<g2, 256, 0, stream>>>(outb, posb, Wo, 256, bo,
                                          R2f, nullptr, 256, 256, 0, 0);
        // attn logits -> awb f32
        mfma_gemm<<<g1, 256, 0, stream>>>(outb, posb, Wa, 256, ba,
                                          awb, nullptr, 128, 256, 0, 0);
        softmax16_kernel<<<(MTOT * NHEADS) / 256, 256, 0, stream>>>(awb);
        sample_kernel<<<MTOT, 256, 0, stream>>>(R1, R2f, awb, sb);
        // attn_out = s @ Wout + bout -> R1 f32
        mfma_gemm<<<g2, 256, 0, stream>>>(sb, nullptr, Wou, 256, bou,
                                          R1, nullptr, 256, 256, 0, 0);
        ln_kernel<<<MTOT / 4, 256, 0, stream>>>(out, outb, R1,
                                                ln1s + (long)i * 256,
                                                ln1b + (long)i * 256);
        // FF in two 512-wide chunks (h aliases R2)
        for (int c = 0; c < 2; ++c) {
            mfma_gemm<<<g4, 256, 0, stream>>>(outb, nullptr,
                                              W1i + (long)c * 512 * 256, 256,
                                              b1i + c * 512,
                                              nullptr, hbuf, 512, 256, 1, 0);
            mfma_gemm<<<g2, 256, 0, stream>>>(hbuf, nullptr,
                                              W2i + (long)c * 512, 1024,
                                              (c == 0) ? b2i : nullptr,
                                              R1, nullptr, 256, 512, 0, c);
        }
        ln_kernel<<<MTOT / 4, 256, 0, stream>>>(out, outb, R1,
                                                ln2s + (long)i * 256,
                                                ln2b + (long)i * 256);
    }
}

// Round 4
// 2891.095 us; speedup vs baseline: 3.2259x; 1.6763x over previous
//
#include <hip/hip_runtime.h>
#include <math.h>

// Problem constants
#define DMODEL 256
#define NHEADS 8
#define NLAY 6
#define DFF 1024
#define DHEAD 32
#define NB 2
#define STOT 21760
#define MTOT (NB * STOT)   // 43520 = 128 * 340

typedef unsigned short u16;
typedef __attribute__((ext_vector_type(8))) short short8;
typedef __attribute__((ext_vector_type(4))) float floatx4;

__device__ __forceinline__ float bf2f(u16 h) {
    unsigned int u = ((unsigned int)h) << 16;
    return __uint_as_float(u);
}
__device__ __forceinline__ u16 f2bf(float f) {
    unsigned int u = __float_as_uint(f);
    u = u + 0x7fffu + ((u >> 16) & 1u);   // RNE
    return (u16)(u >> 16);
}
__device__ __forceinline__ unsigned int addbf2(unsigned int a, unsigned int b) {
    const float lo = bf2f((u16)(a & 0xffffu)) + bf2f((u16)(b & 0xffffu));
    const float hi = bf2f((u16)(a >> 16))     + bf2f((u16)(b >> 16));
    return (unsigned int)f2bf(lo) | ((unsigned int)f2bf(hi) << 16);
}

// ---------------------------------------------------------------------------
// Weight transpose + bf16 cast: W[K,N] f32 -> Wt[N,K] bf16. grid(N/32,K/32,NLAY)
// ---------------------------------------------------------------------------
__global__ __launch_bounds__(256)
void wtrans_kernel(const float* __restrict__ W, u16* __restrict__ Wt,
                   const int K, const int N)
{
    __shared__ float ts[32][33];
    const long lstride = (long)K * N;
    W  += blockIdx.z * lstride;
    Wt += blockIdx.z * lstride;
    const int n0 = blockIdx.x * 32;
    const int k0 = blockIdx.y * 32;
    const int t = threadIdx.x;
    const int nl = t & 31, kl = t >> 5;        // kl 0..7
#pragma unroll
    for (int p = 0; p < 4; ++p) {
        const int k = kl + p * 8;
        ts[k][nl] = W[(long)(k0 + k) * N + n0 + nl];
    }
    __syncthreads();
    const int c = t & 31, r0 = t >> 5;
#pragma unroll
    for (int p = 0; p < 4; ++p) {
        const int r = r0 + p * 8;
        Wt[(long)(n0 + r) * K + k0 + c] = f2bf(ts[c][r]);
    }
}

// ---------------------------------------------------------------------------
// Flatten: src[b,d,y,x] -> out[b,s,d] (f32 + bf16); pos + level_embed -> bf16
// ---------------------------------------------------------------------------
__global__ __launch_bounds__(256)
void flatten_kernel(const float* __restrict__ src, const float* __restrict__ pos,
                    const float* __restrict__ le_row,
                    float* __restrict__ out, u16* __restrict__ outb,
                    u16* __restrict__ posb, int HW, int start)
{
    __shared__ float ts[32][33];
    __shared__ float tp[32][33];
    const int b   = blockIdx.z;
    const int d0  = blockIdx.y * 32;
    const int hw0 = blockIdx.x * 32;
    const int t   = threadIdx.x;
    const int hwl = t & 31;
    const int dl  = t >> 5;
#pragma unroll
    for (int p = 0; p < 4; ++p) {
        const int dd = dl + p * 8;
        const int d  = d0 + dd;
        const long idx = ((long)(b * DMODEL + d)) * HW + hw0 + hwl;
        ts[dd][hwl] = src[idx];
        tp[dd][hwl] = pos[idx] + le_row[d];
    }
    __syncthreads();
    const int dl2  = t & 31;
    const int hwl2 = t >> 5;
#pragma unroll
    for (int p = 0; p < 4; ++p) {
        const int hh  = hwl2 + p * 8;
        const int tok = start + hw0 + hh;
        const long o  = ((long)(b * STOT + tok)) * DMODEL + d0 + dl2;
        const float v = ts[dl2][hh];
        out[o]  = v;
        outb[o] = f2bf(v);
        posb[o] = f2bf(tp[dl2][hh]);
    }
}

// ---------------------------------------------------------------------------
// bf16 MFMA GEMM: C[M,N] = (A1 (+A2))[M,K]bf16 @ Bt[N,K]bf16^T
// 128x128 tile, BK=32, 256 thr = 4 waves (2x2), each wave 4x4 of 16x16x32 MFMA.
// Optional: bias f32[N], accum (+= Cf), relu, f32 out Cf and/or bf16 out Cb.
// ---------------------------------------------------------------------------
__global__ __launch_bounds__(256)
void mfma_gemm(const u16* __restrict__ A1, const u16* __restrict__ A2,
               const u16* __restrict__ Bt, const int ldb,
               const float* __restrict__ bias,
               float* __restrict__ Cf, u16* __restrict__ Cb, const int ldc,
               const int K, const int relu, const int accum)
{
    __shared__ u16 As[128 * 40];
    __shared__ u16 Bs[128 * 40];
    const int tid  = threadIdx.x;
    const int wv   = tid >> 6;
    const int lane = tid & 63;
    const int m0 = blockIdx.y * 128;
    const int n0 = blockIdx.x * 128;
    const int wm = (wv & 1) * 64;
    const int wn = (wv >> 1) * 64;
    const int q   = lane >> 4;
    const int c16 = lane & 15;

    const int srow = tid >> 2;        // 0..63
    const int scol = (tid & 3) * 8;   // 0,8,16,24

    floatx4 acc[4][4];
#pragma unroll
    for (int i = 0; i < 4; ++i)
#pragma unroll
        for (int j = 0; j < 4; ++j)
            acc[i][j] = (floatx4){0.f, 0.f, 0.f, 0.f};

    union Frag { short8 v; uint2 u[2]; };

    for (int k0 = 0; k0 < K; k0 += 32) {
#pragma unroll
        for (int it = 0; it < 2; ++it) {
            const int r = srow + it * 64;
            uint4 va = *(const uint4*)(A1 + (long)(m0 + r) * K + k0 + scol);
            if (A2) {
                const uint4 v2 = *(const uint4*)(A2 + (long)(m0 + r) * K + k0 + scol);
                va.x = addbf2(va.x, v2.x); va.y = addbf2(va.y, v2.y);
                va.z = addbf2(va.z, v2.z); va.w = addbf2(va.w, v2.w);
            }
            uint2 lo, hi;
            lo.x = va.x; lo.y = va.y; hi.x = va.z; hi.y = va.w;
            *(uint2*)&As[r * 40 + scol]     = lo;
            *(uint2*)&As[r * 40 + scol + 4] = hi;
            const uint4 vb = *(const uint4*)(Bt + (long)(n0 + r) * ldb + k0 + scol);
            lo.x = vb.x; lo.y = vb.y; hi.x = vb.z; hi.y = vb.w;
            *(uint2*)&Bs[r * 40 + scol]     = lo;
            *(uint2*)&Bs[r * 40 + scol + 4] = hi;
        }
        __syncthreads();

        short8 af[4], bf[4];
#pragma unroll
        for (int i = 0; i < 4; ++i) {
            Frag fa;
            const int ao = (wm + i * 16 + c16) * 40 + q * 8;
            fa.u[0] = *(const uint2*)&As[ao];
            fa.u[1] = *(const uint2*)&As[ao + 4];
            af[i] = fa.v;
            Frag fb;
            const int bo = (wn + i * 16 + c16) * 40 + q * 8;
            fb.u[0] = *(const uint2*)&Bs[bo];
            fb.u[1] = *(const uint2*)&Bs[bo + 4];
            bf[i] = fb.v;
        }
#pragma unroll
        for (int i = 0; i < 4; ++i)
#pragma unroll
            for (int j = 0; j < 4; ++j)
                acc[i][j] = __builtin_amdgcn_mfma_f32_16x16x32_bf16(
                    af[i], bf[j], acc[i][j], 0, 0, 0);
        __syncthreads();
    }

#pragma unroll
    for (int i = 0; i < 4; ++i) {
#pragma unroll
        for (int j = 0; j < 4; ++j) {
            const int col = n0 + wn + j * 16 + c16;
            const float bv = bias ? bias[col] : 0.f;
#pragma unroll
            for (int r = 0; r < 4; ++r) {
                const int row = m0 + wm + i * 16 + q * 4 + r;
                float v = acc[i][j][r] + bv;
                const long o = (long)row * ldc + col;
                if (accum) v += Cf[o];
                if (relu)  v = fmaxf(v, 0.f);
                if (Cf) Cf[o] = v;
                if (Cb) Cb[o] = f2bf(v);
            }
        }
    }
}

// ---------------------------------------------------------------------------
// Softmax over 16 (l,p) logits per (b,s,head), in place (f32).
// ---------------------------------------------------------------------------
__global__ __launch_bounds__(256)
void softmax16_kernel(float* __restrict__ logits)
{
    const int r = blockIdx.x * 256 + threadIdx.x;
    if (r >= MTOT * NHEADS) return;
    float v[16];
    float mx = -1e30f;
#pragma unroll
    for (int i = 0; i < 16; ++i) { v[i] = logits[(long)r * 16 + i]; mx = fmaxf(mx, v[i]); }
    float s = 0.f;
#pragma unroll
    for (int i = 0; i < 16; ++i) { v[i] = expf(v[i] - mx); s += v[i]; }
    const float inv = 1.f / s;
#pragma unroll
    for (int i = 0; i < 16; ++i) logits[(long)r * 16 + i] = v[i] * inv;
}

// ---------------------------------------------------------------------------
// Deformable sampling from bf16 value. One wave per token: 8 heads x 8 lanes,
// each lane covers 4 channels with 8B (4x bf16) gathers. 4 tokens per block.
// ---------------------------------------------------------------------------
__global__ __launch_bounds__(256)
void sample_kernel(const u16* __restrict__ value, const float* __restrict__ off,
                   const float* __restrict__ aw, u16* __restrict__ outb)
{
    constexpr int LH[4] = {128, 64, 32, 16};
    constexpr int LW[4] = {128, 64, 32, 16};
    constexpr int LS[4] = {0, 16384, 20480, 21504};

    const int t = threadIdx.x;
    const int tl = t >> 6;                 // token within block (wave id)
    const int tid64 = t & 63;
    const int h = tid64 >> 3;              // head 0..7
    const int lane8 = tid64 & 7;           // 0..7 -> 4 channels each
    const int blk = blockIdx.x * 4 + tl;   // global token
    const int b = blk / STOT;
    const int s = blk - b * STOT;

    float refx, refy;
    if (s < 16384) {
        const int yy = s >> 7, xx = s & 127;
        refx = (xx + 0.5f) * (1.f / 128.f); refy = (yy + 0.5f) * (1.f / 128.f);
    } else if (s < 20480) {
        const int sl = s - 16384; const int yy = sl >> 6, xx = sl & 63;
        refx = (xx + 0.5f) * (1.f / 64.f);  refy = (yy + 0.5f) * (1.f / 64.f);
    } else if (s < 21504) {
        const int sl = s - 20480; const int yy = sl >> 5, xx = sl & 31;
        refx = (xx + 0.5f) * (1.f / 32.f);  refy = (yy + 0.5f) * (1.f / 32.f);
    } else {
        const int sl = s - 21504; const int yy = sl >> 4, xx = sl & 15;
        refx = (xx + 0.5f) * (1.f / 16.f);  refy = (yy + 0.5f) * (1.f / 16.f);
    }

    const float* offp = off + (long)blk * 256 + h * 32;
    const float* awp  = aw  + (long)blk * 128 + h * 16;
    const int ch = h * DHEAD + lane8 * 4;  // first of 4 channels
    float a0 = 0.f, a1 = 0.f, a2 = 0.f, a3 = 0.f;
#pragma unroll
    for (int l = 0; l < 4; ++l) {
        const int lw = LW[l], lh = LH[l], ls = LS[l];
        const u16* vbase = value + ((long)(b * STOT + ls)) * DMODEL + ch;
#pragma unroll
        for (int p = 0; p < 4; ++p) {
            const float ox = offp[(l * 4 + p) * 2 + 0];
            const float oy = offp[(l * 4 + p) * 2 + 1];
            const float a  = awp[l * 4 + p];
            const float x = refx * lw + ox - 0.5f;
            const float y = refy * lh + oy - 0.5f;
            const float x0f = floorf(x), y0f = floorf(y);
            const float lx = x - x0f, ly = y - y0f;
            const int x0 = (int)x0f, y0 = (int)y0f;
#pragma unroll
            for (int dy = 0; dy < 2; ++dy) {
                const int yi = y0 + dy;
                if (yi < 0 || yi >= lh) continue;
                const float wy = dy ? ly : (1.f - ly);
#pragma unroll
                for (int dx = 0; dx < 2; ++dx) {
                    const int xi = x0 + dx;
                    if (xi < 0 || xi >= lw) continue;
                    const float wx = dx ? lx : (1.f - lx);
                    const float w = a * wy * wx;
                    const uint2 d = *(const uint2*)(vbase + (long)(yi * lw + xi) * DMODEL);
                    a0 = fmaf(w, __uint_as_float(d.x << 16), a0);
                    a1 = fmaf(w, __uint_as_float(d.x & 0xffff0000u), a1);
                    a2 = fmaf(w, __uint_as_float(d.y << 16), a2);
                    a3 = fmaf(w, __uint_as_float(d.y & 0xffff0000u), a3);
                }
            }
        }
    }
    ushort4 r;
    r.x = f2bf(a0); r.y = f2bf(a1); r.z = f2bf(a2); r.w = f2bf(a3);
    *(ushort4*)(outb + (long)blk * DMODEL + ch) = r;
}

// ---------------------------------------------------------------------------
// out = LayerNorm(out + delta); writes f32 (residual) + bf16 (next GEMM A).
// ---------------------------------------------------------------------------
__global__ __launch_bounds__(256)
void ln_kernel(float* __restrict__ out, u16* __restrict__ outb,
               const float* __restrict__ delta,
               const float* __restrict__ gamma, const float* __restrict__ beta)
{
    const int wave = threadIdx.x >> 6;
    const int lane = threadIdx.x & 63;
    const long tok = (long)blockIdx.x * 4 + wave;
    float* op = out + tok * DMODEL + lane * 4;
    const float4 xo = *(const float4*)op;
    const float4 dd = *(const float4*)(delta + tok * DMODEL + lane * 4);
    float x[4] = {xo.x + dd.x, xo.y + dd.y, xo.z + dd.z, xo.w + dd.w};

    float sum = x[0] + x[1] + x[2] + x[3];
#pragma unroll
    for (int o = 32; o >= 1; o >>= 1) sum += __shfl_xor(sum, o);
    const float mean = sum * (1.f / 256.f);

    float vs = 0.f;
#pragma unroll
    for (int i = 0; i < 4; ++i) { const float d2 = x[i] - mean; vs += d2 * d2; }
#pragma unroll
    for (int o = 32; o >= 1; o >>= 1) vs += __shfl_xor(vs, o);
    const float rstd = rsqrtf(vs * (1.f / 256.f) + 1e-5f);

    const float4 g  = *(const float4*)(gamma + lane * 4);
    const float4 be = *(const float4*)(beta + lane * 4);
    float4 r;
    r.x = (x[0] - mean) * rstd * g.x + be.x;
    r.y = (x[1] - mean) * rstd * g.y + be.y;
    r.z = (x[2] - mean) * rstd * g.z + be.z;
    r.w = (x[3] - mean) * rstd * g.w + be.w;
    *(float4*)op = r;
    ushort4 rb;
    rb.x = f2bf(r.x); rb.y = f2bf(r.y); rb.z = f2bf(r.z); rb.w = f2bf(r.w);
    *(ushort4*)(outb + tok * DMODEL + lane * 4) = rb;
}

// ---------------------------------------------------------------------------
extern "C" void kernel_launch(void* const* d_in, const int* in_sizes, int n_in,
                              void* d_out, int out_size, void* d_ws, size_t ws_size,
                              hipStream_t stream)
{
    const float* src[4] = {(const float*)d_in[0], (const float*)d_in[2],
                           (const float*)d_in[4], (const float*)d_in[6]};
    const float* pos[4] = {(const float*)d_in[1], (const float*)d_in[3],
                           (const float*)d_in[5], (const float*)d_in[7]};
    const float* level_embed = (const float*)d_in[8];
    const float* Woff  = (const float*)d_in[9];
    const float* boff  = (const float*)d_in[10];
    const float* Wattn = (const float*)d_in[11];
    const float* battn = (const float*)d_in[12];
    const float* Wval  = (const float*)d_in[13];
    const float* bval  = (const float*)d_in[14];
    const float* Wout  = (const float*)d_in[15];
    const float* bout  = (const float*)d_in[16];
    const float* ln1s  = (const float*)d_in[17];
    const float* ln1b  = (const float*)d_in[18];
    const float* W1    = (const float*)d_in[19];
    const float* b1    = (const float*)d_in[20];
    const float* W2    = (const float*)d_in[21];
    const float* b2    = (const float*)d_in[22];
    const float* ln2s  = (const float*)d_in[23];
    const float* ln2b  = (const float*)d_in[24];

    float* out = (float*)d_out;                       // residual stream f32
    const long MD = (long)MTOT * DMODEL;              // 11,141,120

    // workspace layout (~188 MB total)
    u16*   outb = (u16*)d_ws;                         // [M,256] bf16
    u16*   posb = outb + MD;                          // [M,256] bf16
    float* R1   = (float*)(posb + MD);                // [M,256] f32: attn_out/ff_out
    u16*   vb   = (u16*)R1;                           //   [M,256] bf16 value (pre-Wout phase)
    float* R2f  = R1 + MD;                            // [M,256] f32 offsets  (aliases h)
    u16*   hbuf = (u16*)R2f;                          //   [M,512] bf16 FF hidden chunk
    float* awb  = R2f + MD;                           // [M,128] f32 attn weights
    u16*   sb   = (u16*)(awb + (long)MTOT * 128);     // [M,256] bf16 sampled
    u16*   wts  = sb + MD;                            // bf16 transposed weights
    u16* Wvalt  = wts;
    u16* Wofft  = Wvalt  + 6L * 256 * 256;
    u16* Wattnt = Wofft  + 6L * 256 * 256;
    u16* Woutt  = Wattnt + 6L * 128 * 256;
    u16* W1t    = Woutt  + 6L * 256 * 256;
    u16* W2t    = W1t    + 6L * 1024 * 256;

    // ---- weight transpose+cast (runs every call; ~9 MB total) ----
    wtrans_kernel<<<dim3(8, 8, 6),  256, 0, stream>>>(Wval,  Wvalt,  256, 256);
    wtrans_kernel<<<dim3(8, 8, 6),  256, 0, stream>>>(Woff,  Wofft,  256, 256);
    wtrans_kernel<<<dim3(4, 8, 6),  256, 0, stream>>>(Wattn, Wattnt, 256, 128);
    wtrans_kernel<<<dim3(8, 8, 6),  256, 0, stream>>>(Wout,  Woutt,  256, 256);
    wtrans_kernel<<<dim3(32, 8, 6), 256, 0, stream>>>(W1,    W1t,    256, 1024);
    wtrans_kernel<<<dim3(8, 32, 6), 256, 0, stream>>>(W2,    W2t,    1024, 256);

    // ---- flatten ----
    {
        const int HW[4] = {16384, 4096, 1024, 256};
        const int ST[4] = {0, 16384, 20480, 21504};
        for (int l = 0; l < 4; ++l) {
            dim3 g(HW[l] / 32, DMODEL / 32, NB);
            flatten_kernel<<<g, 256, 0, stream>>>(src[l], pos[l],
                                                  level_embed + l * DMODEL,
                                                  out, outb, posb, HW[l], ST[l]);
        }
    }

    const dim3 g2(2, MTOT / 128);
    const dim3 g1(1, MTOT / 128);
    const dim3 g4(4, MTOT / 128);

    for (int i = 0; i < NLAY; ++i) {
        const u16* Wv  = Wvalt  + (long)i * 256 * 256;
        const u16* Wo  = Wofft  + (long)i * 256 * 256;
        const u16* Wa  = Wattnt + (long)i * 128 * 256;
        const u16* Wou = Woutt  + (long)i * 256 * 256;
        const u16* W1i = W1t    + (long)i * 1024 * 256;
        const u16* W2i = W2t    + (long)i * 256 * 1024;
        const float* bv  = bval  + (long)i * 256;
        const float* bo  = boff  + (long)i * 256;
        const float* ba  = battn + (long)i * 128;
        const float* bou = bout  + (long)i * 256;
        const float* b1i = b1    + (long)i * DFF;
        const float* b2i = b2    + (long)i * 256;

        // value = out @ Wval + bval   -> vb bf16 (aliases R1; Wout GEMM writes
        // R1 only after sample_kernel has consumed vb — same-stream ordering)
        mfma_gemm<<<g2, 256, 0, stream>>>(outb, nullptr, Wv, 256, bv,
                                          nullptr, vb, 256, 256, 0, 0);
        // off = (out+pos) @ Woff + boff -> R2 f32
        mfma_gemm<<<g2, 256, 0, stream>>>(outb, posb, Wo, 256, bo,
                                          R2f, nullptr, 256, 256, 0, 0);
        // attn logits -> awb f32
        mfma_gemm<<<g1, 256, 0, stream>>>(outb, posb, Wa, 256, ba,
                                          awb, nullptr, 128, 256, 0, 0);
        softmax16_kernel<<<(MTOT * NHEADS) / 256, 256, 0, stream>>>(awb);
        sample_kernel<<<MTOT / 4, 256, 0, stream>>>(vb, R2f, awb, sb);
        // attn_out = s @ Wout + bout -> R1 f32
        mfma_gemm<<<g2, 256, 0, stream>>>(sb, nullptr, Wou, 256, bou,
                                          R1, nullptr, 256, 256, 0, 0);
        ln_kernel<<<MTOT / 4, 256, 0, stream>>>(out, outb, R1,
                                                ln1s + (long)i * 256,
                                                ln1b + (long)i * 256);
        // FF in two 512-wide chunks (h aliases R2)
        for (int c = 0; c < 2; ++c) {
            mfma_gemm<<<g4, 256, 0, stream>>>(outb, nullptr,
                                              W1i + (long)c * 512 * 256, 256,
                                              b1i + c * 512,
                                              nullptr, hbuf, 512, 256, 1, 0);
            mfma_gemm<<<g2, 256, 0, stream>>>(hbuf, nullptr,
                                              W2i + (long)c * 512, 1024,
                                              (c == 0) ? b2i : nullptr,
                                              R1, nullptr, 256, 512, 0, c);
        }
        ln_kernel<<<MTOT / 4, 256, 0, stream>>>(out, outb, R1,
                                                ln2s + (long)i * 256,
                                                ln2b + (long)i * 256);
    }
}

// Round 5
// 2383.023 us; speedup vs baseline: 3.9137x; 1.2132x over previous
//
#include <hip/hip_runtime.h>
#include <math.h>

// Problem constants
#define DMODEL 256
#define NHEADS 8
#define NLAY 6
#define DFF 1024
#define DHEAD 32
#define NB 2
#define STOT 21760
#define MTOT (NB * STOT)   // 43520 = 128 * 340

typedef unsigned short u16;
typedef __attribute__((ext_vector_type(8))) short short8;
typedef __attribute__((ext_vector_type(4))) float floatx4;

__device__ __forceinline__ float bf2f(u16 h) {
    unsigned int u = ((unsigned int)h) << 16;
    return __uint_as_float(u);
}
__device__ __forceinline__ u16 f2bf(float f) {
    unsigned int u = __float_as_uint(f);
    u = u + 0x7fffu + ((u >> 16) & 1u);   // RNE
    return (u16)(u >> 16);
}

// ---------------------------------------------------------------------------
// Concatenated bias [NLAY][384] = boff[i] (256) || battn[i] (128)
// ---------------------------------------------------------------------------
__global__ __launch_bounds__(256)
void biascat_kernel(const float* __restrict__ boff, const float* __restrict__ battn,
                    float* __restrict__ bias384)
{
    const int t = blockIdx.x * 256 + threadIdx.x;
    if (t >= NLAY * 384) return;
    const int i = t / 384, c = t - i * 384;
    bias384[t] = (c < 256) ? boff[i * 256 + c] : battn[i * 128 + (c - 256)];
}

// ---------------------------------------------------------------------------
// Weight transpose + bf16 cast: W[K,N] f32 -> Wt[N,K] bf16.
// grid(N/32, K/32, NLAY); separate per-layer strides for src/dst.
// ---------------------------------------------------------------------------
__global__ __launch_bounds__(256)
void wtrans_kernel(const float* __restrict__ W, u16* __restrict__ Wt,
                   const int K, const int N, const long wstride, const long ostride)
{
    __shared__ float ts[32][33];
    W  += blockIdx.z * wstride;
    Wt += blockIdx.z * ostride;
    const int n0 = blockIdx.x * 32;
    const int k0 = blockIdx.y * 32;
    const int t = threadIdx.x;
    const int nl = t & 31, kl = t >> 5;        // kl 0..7
#pragma unroll
    for (int p = 0; p < 4; ++p) {
        const int k = kl + p * 8;
        ts[k][nl] = W[(long)(k0 + k) * N + n0 + nl];
    }
    __syncthreads();
    const int c = t & 31, r0 = t >> 5;
#pragma unroll
    for (int p = 0; p < 4; ++p) {
        const int r = r0 + p * 8;
        Wt[(long)(n0 + r) * K + k0 + c] = f2bf(ts[c][r]);
    }
}

// ---------------------------------------------------------------------------
// Flatten: src[b,d,y,x] -> out f32, outb bf16, posb bf16, qb = bf16(src+pos+le)
// ---------------------------------------------------------------------------
__global__ __launch_bounds__(256)
void flatten_kernel(const float* __restrict__ src, const float* __restrict__ pos,
                    const float* __restrict__ le_row,
                    float* __restrict__ out, u16* __restrict__ outb,
                    u16* __restrict__ posb, u16* __restrict__ qb,
                    int HW, int start)
{
    __shared__ float ts[32][33];
    __shared__ float tp[32][33];
    const int b   = blockIdx.z;
    const int d0  = blockIdx.y * 32;
    const int hw0 = blockIdx.x * 32;
    const int t   = threadIdx.x;
    const int hwl = t & 31;
    const int dl  = t >> 5;
#pragma unroll
    for (int p = 0; p < 4; ++p) {
        const int dd = dl + p * 8;
        const int d  = d0 + dd;
        const long idx = ((long)(b * DMODEL + d)) * HW + hw0 + hwl;
        ts[dd][hwl] = src[idx];
        tp[dd][hwl] = pos[idx] + le_row[d];
    }
    __syncthreads();
    const int dl2  = t & 31;
    const int hwl2 = t >> 5;
#pragma unroll
    for (int p = 0; p < 4; ++p) {
        const int hh  = hwl2 + p * 8;
        const int tok = start + hw0 + hh;
        const long o  = ((long)(b * STOT + tok)) * DMODEL + d0 + dl2;
        const float v = ts[dl2][hh];
        const float pp = tp[dl2][hh];
        out[o]  = v;
        outb[o] = f2bf(v);
        posb[o] = f2bf(pp);
        qb[o]   = f2bf(v + pp);
    }
}

// ---------------------------------------------------------------------------
// bf16 MFMA GEMM: Cb[M,N]bf16 = A[M,K]bf16 @ Bt[N,K]bf16^T + bias (relu opt)
// 128x128 tile, BK=32, 256 thr = 4 waves (2x2), each wave 4x4 of 16x16x32 MFMA.
// If Cb2 != null and n0 >= 256: write to Cb2 with ld 128, col-256 (merged
// off||attn output split).
// ---------------------------------------------------------------------------
__global__ __launch_bounds__(256)
void mfma_gemm(const u16* __restrict__ A, const u16* __restrict__ Bt,
               const int ldb, const float* __restrict__ bias,
               u16* __restrict__ Cb, const int ldc, u16* __restrict__ Cb2,
               const int K, const int relu)
{
    __shared__ u16 As[128 * 40];
    __shared__ u16 Bs[128 * 40];
    const int tid  = threadIdx.x;
    const int wv   = tid >> 6;
    const int lane = tid & 63;
    const int m0 = blockIdx.y * 128;
    const int n0 = blockIdx.x * 128;
    const int wm = (wv & 1) * 64;
    const int wn = (wv >> 1) * 64;
    const int q   = lane >> 4;
    const int c16 = lane & 15;

    const int srow = tid >> 2;        // 0..63
    const int scol = (tid & 3) * 8;   // 0,8,16,24

    floatx4 acc[4][4];
#pragma unroll
    for (int i = 0; i < 4; ++i)
#pragma unroll
        for (int j = 0; j < 4; ++j)
            acc[i][j] = (floatx4){0.f, 0.f, 0.f, 0.f};

    union Frag { short8 v; uint2 u[2]; };

    for (int k0 = 0; k0 < K; k0 += 32) {
#pragma unroll
        for (int it = 0; it < 2; ++it) {
            const int r = srow + it * 64;
            const uint4 va = *(const uint4*)(A + (long)(m0 + r) * K + k0 + scol);
            uint2 lo, hi;
            lo.x = va.x; lo.y = va.y; hi.x = va.z; hi.y = va.w;
            *(uint2*)&As[r * 40 + scol]     = lo;
            *(uint2*)&As[r * 40 + scol + 4] = hi;
            const uint4 vb = *(const uint4*)(Bt + (long)(n0 + r) * ldb + k0 + scol);
            lo.x = vb.x; lo.y = vb.y; hi.x = vb.z; hi.y = vb.w;
            *(uint2*)&Bs[r * 40 + scol]     = lo;
            *(uint2*)&Bs[r * 40 + scol + 4] = hi;
        }
        __syncthreads();

        short8 af[4], bf[4];
#pragma unroll
        for (int i = 0; i < 4; ++i) {
            Frag fa;
            const int ao = (wm + i * 16 + c16) * 40 + q * 8;
            fa.u[0] = *(const uint2*)&As[ao];
            fa.u[1] = *(const uint2*)&As[ao + 4];
            af[i] = fa.v;
            Frag fb;
            const int bo = (wn + i * 16 + c16) * 40 + q * 8;
            fb.u[0] = *(const uint2*)&Bs[bo];
            fb.u[1] = *(const uint2*)&Bs[bo + 4];
            bf[i] = fb.v;
        }
#pragma unroll
        for (int i = 0; i < 4; ++i)
#pragma unroll
            for (int j = 0; j < 4; ++j)
                acc[i][j] = __builtin_amdgcn_mfma_f32_16x16x32_bf16(
                    af[i], bf[j], acc[i][j], 0, 0, 0);
        __syncthreads();
    }

    // output selection (block-uniform)
    u16* cb  = Cb;
    int ldcb = ldc, csub = 0;
    if (Cb2 && n0 >= 256) { cb = Cb2; ldcb = 128; csub = 256; }

#pragma unroll
    for (int i = 0; i < 4; ++i) {
#pragma unroll
        for (int j = 0; j < 4; ++j) {
            const int col = n0 + wn + j * 16 + c16;
            const float bv = bias ? bias[col] : 0.f;
#pragma unroll
            for (int r = 0; r < 4; ++r) {
                const int row = m0 + wm + i * 16 + q * 4 + r;
                float v = acc[i][j][r] + bv;
                if (relu) v = fmaxf(v, 0.f);
                cb[(long)row * ldcb + col - csub] = f2bf(v);
            }
        }
    }
}

// ---------------------------------------------------------------------------
// Softmax over 16 bf16 logits per (b,s,head), in place.
// ---------------------------------------------------------------------------
__global__ __launch_bounds__(256)
void softmax16_kernel(u16* __restrict__ aw)
{
    const int r = blockIdx.x * 256 + threadIdx.x;
    if (r >= MTOT * NHEADS) return;
    u16* p = aw + (long)r * 16;
    const uint4 da = *(const uint4*)p;
    const uint4 dbv = *(const uint4*)(p + 8);
    uint u[8] = {da.x, da.y, da.z, da.w, dbv.x, dbv.y, dbv.z, dbv.w};
    float v[16];
    float mx = -1e30f;
#pragma unroll
    for (int j = 0; j < 8; ++j) {
        v[2 * j]     = bf2f((u16)(u[j] & 0xffffu));
        v[2 * j + 1] = bf2f((u16)(u[j] >> 16));
        mx = fmaxf(mx, fmaxf(v[2 * j], v[2 * j + 1]));
    }
    float s = 0.f;
#pragma unroll
    for (int i = 0; i < 16; ++i) { v[i] = expf(v[i] - mx); s += v[i]; }
    const float inv = 1.f / s;
#pragma unroll
    for (int j = 0; j < 8; ++j)
        u[j] = (uint)f2bf(v[2 * j] * inv) | ((uint)f2bf(v[2 * j + 1] * inv) << 16);
    uint4 oa; oa.x = u[0]; oa.y = u[1]; oa.z = u[2]; oa.w = u[3];
    uint4 ob; ob.x = u[4]; ob.y = u[5]; ob.z = u[6]; ob.w = u[7];
    *(uint4*)p = oa;
    *(uint4*)(p + 8) = ob;
}

// ---------------------------------------------------------------------------
// Deformable sampling, all-bf16 inputs. One wave per token: 8 heads x 8 lanes,
// each lane covers 4 channels with 8B gathers. 4 tokens per block.
// ---------------------------------------------------------------------------
__global__ __launch_bounds__(256)
void sample_kernel(const u16* __restrict__ value, const u16* __restrict__ offb,
                   const u16* __restrict__ aw, u16* __restrict__ sb)
{
    constexpr int LH[4] = {128, 64, 32, 16};
    constexpr int LW[4] = {128, 64, 32, 16};
    constexpr int LS[4] = {0, 16384, 20480, 21504};

    const int t = threadIdx.x;
    const int tl = t >> 6;                 // token within block (wave id)
    const int tid64 = t & 63;
    const int h = tid64 >> 3;              // head 0..7
    const int lane8 = tid64 & 7;           // 0..7 -> 4 channels each
    const int blk = blockIdx.x * 4 + tl;   // global token
    const int b = blk / STOT;
    const int s = blk - b * STOT;

    float refx, refy;
    if (s < 16384) {
        const int yy = s >> 7, xx = s & 127;
        refx = (xx + 0.5f) * (1.f / 128.f); refy = (yy + 0.5f) * (1.f / 128.f);
    } else if (s < 20480) {
        const int sl = s - 16384; const int yy = sl >> 6, xx = sl & 63;
        refx = (xx + 0.5f) * (1.f / 64.f);  refy = (yy + 0.5f) * (1.f / 64.f);
    } else if (s < 21504) {
        const int sl = s - 20480; const int yy = sl >> 5, xx = sl & 31;
        refx = (xx + 0.5f) * (1.f / 32.f);  refy = (yy + 0.5f) * (1.f / 32.f);
    } else {
        const int sl = s - 21504; const int yy = sl >> 4, xx = sl & 15;
        refx = (xx + 0.5f) * (1.f / 16.f);  refy = (yy + 0.5f) * (1.f / 16.f);
    }

    const u16* offp = offb + (long)blk * 256 + h * 32;
    const u16* awp  = aw   + (long)blk * 128 + h * 16;
    const int ch = h * DHEAD + lane8 * 4;  // first of 4 channels
    float a0 = 0.f, a1 = 0.f, a2 = 0.f, a3 = 0.f;
#pragma unroll
    for (int l = 0; l < 4; ++l) {
        const int lw = LW[l], lh = LH[l], ls = LS[l];
        const u16* vbase = value + ((long)(b * STOT + ls)) * DMODEL + ch;
#pragma unroll
        for (int p = 0; p < 4; ++p) {
            const uint o2 = *(const uint*)(offp + (l * 4 + p) * 2);
            const float ox = bf2f((u16)(o2 & 0xffffu));
            const float oy = bf2f((u16)(o2 >> 16));
            const float a  = bf2f(awp[l * 4 + p]);
            const float x = refx * lw + ox - 0.5f;
            const float y = refy * lh + oy - 0.5f;
            const float x0f = floorf(x), y0f = floorf(y);
            const float lx = x - x0f, ly = y - y0f;
            const int x0 = (int)x0f, y0 = (int)y0f;
#pragma unroll
            for (int dy = 0; dy < 2; ++dy) {
                const int yi = y0 + dy;
                if (yi < 0 || yi >= lh) continue;
                const float wy = dy ? ly : (1.f - ly);
#pragma unroll
                for (int dx = 0; dx < 2; ++dx) {
                    const int xi = x0 + dx;
                    if (xi < 0 || xi >= lw) continue;
                    const float wx = dx ? lx : (1.f - lx);
                    const float w = a * wy * wx;
                    const uint2 d = *(const uint2*)(vbase + (long)(yi * lw + xi) * DMODEL);
                    a0 = fmaf(w, __uint_as_float(d.x << 16), a0);
                    a1 = fmaf(w, __uint_as_float(d.x & 0xffff0000u), a1);
                    a2 = fmaf(w, __uint_as_float(d.y << 16), a2);
                    a3 = fmaf(w, __uint_as_float(d.y & 0xffff0000u), a3);
                }
            }
        }
    }
    ushort4 r;
    r.x = f2bf(a0); r.y = f2bf(a1); r.z = f2bf(a2); r.w = f2bf(a3);
    *(ushort4*)(sb + (long)blk * DMODEL + ch) = r;
}

// ---------------------------------------------------------------------------
// out = LayerNorm(out + delta_bf16); writes f32 residual + bf16 outb.
// If qb != null: also writes qb = bf16(LNout + posb) for next layer's q-GEMM.
// ---------------------------------------------------------------------------
__global__ __launch_bounds__(256)
void ln_kernel(float* __restrict__ out, u16* __restrict__ outb,
               u16* __restrict__ qb, const u16* __restrict__ posb,
               const u16* __restrict__ db,
               const float* __restrict__ gamma, const float* __restrict__ beta)
{
    const int wave = threadIdx.x >> 6;
    const int lane = threadIdx.x & 63;
    const long tok = (long)blockIdx.x * 4 + wave;
    float* op = out + tok * DMODEL + lane * 4;
    const float4 xo = *(const float4*)op;
    const ushort4 d4 = *(const ushort4*)(db + tok * DMODEL + lane * 4);
    float x[4] = {xo.x + bf2f(d4.x), xo.y + bf2f(d4.y),
                  xo.z + bf2f(d4.z), xo.w + bf2f(d4.w)};

    float sum = x[0] + x[1] + x[2] + x[3];
#pragma unroll
    for (int o = 32; o >= 1; o >>= 1) sum += __shfl_xor(sum, o);
    const float mean = sum * (1.f / 256.f);

    float vs = 0.f;
#pragma unroll
    for (int i = 0; i < 4; ++i) { const float d2 = x[i] - mean; vs += d2 * d2; }
#pragma unroll
    for (int o = 32; o >= 1; o >>= 1) vs += __shfl_xor(vs, o);
    const float rstd = rsqrtf(vs * (1.f / 256.f) + 1e-5f);

    const float4 g  = *(const float4*)(gamma + lane * 4);
    const float4 be = *(const float4*)(beta + lane * 4);
    float r[4];
    r[0] = (x[0] - mean) * rstd * g.x + be.x;
    r[1] = (x[1] - mean) * rstd * g.y + be.y;
    r[2] = (x[2] - mean) * rstd * g.z + be.z;
    r[3] = (x[3] - mean) * rstd * g.w + be.w;
    float4 rf; rf.x = r[0]; rf.y = r[1]; rf.z = r[2]; rf.w = r[3];
    *(float4*)op = rf;
    ushort4 rb;
    rb.x = f2bf(r[0]); rb.y = f2bf(r[1]); rb.z = f2bf(r[2]); rb.w = f2bf(r[3]);
    *(ushort4*)(outb + tok * DMODEL + lane * 4) = rb;
    if (qb) {
        const ushort4 p4 = *(const ushort4*)(posb + tok * DMODEL + lane * 4);
        ushort4 qv;
        qv.x = f2bf(r[0] + bf2f(p4.x));
        qv.y = f2bf(r[1] + bf2f(p4.y));
        qv.z = f2bf(r[2] + bf2f(p4.z));
        qv.w = f2bf(r[3] + bf2f(p4.w));
        *(ushort4*)(qb + tok * DMODEL + lane * 4) = qv;
    }
}

// ---------------------------------------------------------------------------
extern "C" void kernel_launch(void* const* d_in, const int* in_sizes, int n_in,
                              void* d_out, int out_size, void* d_ws, size_t ws_size,
                              hipStream_t stream)
{
    const float* src[4] = {(const float*)d_in[0], (const float*)d_in[2],
                           (const float*)d_in[4], (const float*)d_in[6]};
    const float* pos[4] = {(const float*)d_in[1], (const float*)d_in[3],
                           (const float*)d_in[5], (const float*)d_in[7]};
    const float* level_embed = (const float*)d_in[8];
    const float* Woff  = (const float*)d_in[9];
    const float* boff  = (const float*)d_in[10];
    const float* Wattn = (const float*)d_in[11];
    const float* battn = (const float*)d_in[12];
    const float* Wval  = (const float*)d_in[13];
    const float* bval  = (const float*)d_in[14];
    const float* Wout  = (const float*)d_in[15];
    const float* bout  = (const float*)d_in[16];
    const float* ln1s  = (const float*)d_in[17];
    const float* ln1b  = (const float*)d_in[18];
    const float* W1    = (const float*)d_in[19];
    const float* b1    = (const float*)d_in[20];
    const float* W2    = (const float*)d_in[21];
    const float* b2    = (const float*)d_in[22];
    const float* ln2s  = (const float*)d_in[23];
    const float* ln2b  = (const float*)d_in[24];

    float* out = (float*)d_out;                       // residual stream f32
    const long MD = (long)MTOT * DMODEL;              // 11,141,120

    // workspace layout (~187 MB)
    u16* outb = (u16*)d_ws;          // [M,256] LN output bf16
    u16* posb = outb + MD;           // [M,256] pos_flat bf16
    u16* qb   = posb + MD;           // [M,256] q = out+pos bf16
    u16* db   = qb + MD;             // [M,256] delta bf16 (attn_out / ff_out)
    u16* vb   = db + MD;             // [M,256] value bf16      (hb region start)
    u16* offb = vb + MD;             // [M,256] offsets bf16
    u16* awb  = offb + MD;           // [M,128] attn weights bf16
    u16* sb   = awb + MD / 2;        // [M,256] sampled bf16
    u16* hb   = vb;                  // [M,1024] FF hidden (aliases vb..sb+pad)
    u16* wts  = vb + 4 * MD;         // bf16 transposed weights
    u16* Wvalt = wts;
    u16* Wofat = Wvalt + 6L * 256 * 256;   // [384,256] per layer: Woff^T||Wattn^T
    u16* Woutt = Wofat + 6L * 384 * 256;
    u16* W1t   = Woutt + 6L * 256 * 256;
    u16* W2t   = W1t   + 6L * 1024 * 256;
    float* bias384 = (float*)(W2t + 6L * 1024 * 256);  // [NLAY][384]

    // ---- weight prep (every call; ~9 MB) ----
    biascat_kernel<<<9, 256, 0, stream>>>(boff, battn, bias384);
    wtrans_kernel<<<dim3(8, 8, 6),  256, 0, stream>>>(Wval,  Wvalt, 256, 256,
                                                      65536, 65536);
    wtrans_kernel<<<dim3(8, 8, 6),  256, 0, stream>>>(Woff,  Wofat, 256, 256,
                                                      65536, 98304);
    wtrans_kernel<<<dim3(4, 8, 6),  256, 0, stream>>>(Wattn, Wofat + 256 * 256,
                                                      256, 128, 32768, 98304);
    wtrans_kernel<<<dim3(8, 8, 6),  256, 0, stream>>>(Wout,  Woutt, 256, 256,
                                                      65536, 65536);
    wtrans_kernel<<<dim3(32, 8, 6), 256, 0, stream>>>(W1,    W1t, 256, 1024,
                                                      262144, 262144);
    wtrans_kernel<<<dim3(8, 32, 6), 256, 0, stream>>>(W2,    W2t, 1024, 256,
                                                      262144, 262144);

    // ---- flatten ----
    {
        const int HW[4] = {16384, 4096, 1024, 256};
        const int ST[4] = {0, 16384, 20480, 21504};
        for (int l = 0; l < 4; ++l) {
            dim3 g(HW[l] / 32, DMODEL / 32, NB);
            flatten_kernel<<<g, 256, 0, stream>>>(src[l], pos[l],
                                                  level_embed + l * DMODEL,
                                                  out, outb, posb, qb, HW[l], ST[l]);
        }
    }

    const dim3 g2(2, MTOT / 128);   // N=256
    const dim3 g3(3, MTOT / 128);   // N=384 (merged off||attn)
    const dim3 g8(8, MTOT / 128);   // N=1024 (FF1)

    for (int i = 0; i < NLAY; ++i) {
        const u16* Wv  = Wvalt + (long)i * 256 * 256;
        const u16* Wqa = Wofat + (long)i * 384 * 256;
        const u16* Wou = Woutt + (long)i * 256 * 256;
        const u16* W1i = W1t   + (long)i * 1024 * 256;
        const u16* W2i = W2t   + (long)i * 256 * 1024;
        const float* bv  = bval + (long)i * 256;
        const float* bqa = bias384 + (long)i * 384;
        const float* bou = bout + (long)i * 256;
        const float* b1i = b1   + (long)i * DFF;
        const float* b2i = b2   + (long)i * 256;

        // value = out @ Wval + bval -> vb bf16
        mfma_gemm<<<g2, 256, 0, stream>>>(outb, Wv, 256, bv,
                                          vb, 256, nullptr, 256, 0);
        // [off | attn logits] = q @ [Woff|Wattn] -> offb bf16, awb bf16
        mfma_gemm<<<g3, 256, 0, stream>>>(qb, Wqa, 256, bqa,
                                          offb, 256, awb, 256, 0);
        softmax16_kernel<<<(MTOT * NHEADS) / 256, 256, 0, stream>>>(awb);
        sample_kernel<<<MTOT / 4, 256, 0, stream>>>(vb, offb, awb, sb);
        // attn_out = s @ Wout + bout -> db bf16
        mfma_gemm<<<g2, 256, 0, stream>>>(sb, Wou, 256, bou,
                                          db, 256, nullptr, 256, 0);
        ln_kernel<<<MTOT / 4, 256, 0, stream>>>(out, outb, nullptr, nullptr, db,
                                                ln1s + (long)i * 256,
                                                ln1b + (long)i * 256);
        // FF: h = relu(out @ W1 + b1) -> hb bf16 [M,1024]
        mfma_gemm<<<g8, 256, 0, stream>>>(outb, W1i, 256, b1i,
                                          hb, 1024, nullptr, 256, 1);
        // ff_out = h @ W2 + b2 -> db bf16
        mfma_gemm<<<g2, 256, 0, stream>>>(hb, W2i, 1024, b2i,
                                          db, 256, nullptr, 1024, 0);
        ln_kernel<<<MTOT / 4, 256, 0, stream>>>(out, outb, qb, posb, db,
                                                ln2s + (long)i * 256,
                                                ln2b + (long)i * 256);
    }
}